// Round 1
// baseline (5763.212 us; speedup 1.0000x reference)
//
#include <hip/hip_runtime.h>
#include <hip/hip_bf16.h>
#include <stdint.h>

// Problem dims
#define B_   16
#define T_   4096
#define F_   47
#define HID_ 64
#define CH_  256
#define TG_  1024   // T/4
#define G3_  768    // 3*CH

using bf16x8 = __attribute__((ext_vector_type(8))) short;  // 8 bf16 (4 VGPRs)
using f32x4  = __attribute__((ext_vector_type(4))) float;  // 4 fp32 acc
using f16x8  = __attribute__((ext_vector_type(8))) _Float16;

__device__ __forceinline__ short f2bf(float f) {
    union { float f; uint32_t u; } v; v.f = f;
    uint32_t u = v.u;
    uint32_t r = (u + 0x7fffu + ((u >> 16) & 1u)) >> 16;   // RNE
    return (short)r;
}
__device__ __forceinline__ float bf2f(short s) {
    union { uint32_t u; float f; } v; v.u = ((uint32_t)(uint16_t)s) << 16;
    return v.f;
}
__device__ __forceinline__ float fast_tanh(float x) {
    float e = __expf(2.f * x);           // inf-safe
    return 1.f - 2.f / (e + 1.f);
}
__device__ __forceinline__ float fast_sigmoid(float x) {
    return 1.f / (1.f + __expf(-x));
}

#if __has_builtin(__builtin_amdgcn_global_load_lds)
#define HAS_GLL 1
__device__ __forceinline__ void gl_lds16(const void* g, void* l) {
    __builtin_amdgcn_global_load_lds(
        (const __attribute__((address_space(1))) uint32_t*)g,
        (__attribute__((address_space(3))) uint32_t*)l, 16, 0, 0);
}
#else
#define HAS_GLL 0
#endif

// ---------------------------------------------------------------------------
// K1: conv1 (pointwise 47->64) + tanh, fp32 VALU, writes c1 as bf16
__global__ __launch_bounds__(256) void k1_conv1(const float* __restrict__ feat,
        const float* __restrict__ W1, const float* __restrict__ b1,
        short* __restrict__ c1) {
    __shared__ float sW[47 * 64];
    __shared__ float sF[4 * 47];
    int tid = threadIdx.x;
    int b = blockIdx.x >> 10, t0 = (blockIdx.x & 1023) * 4;
    if (tid < 188) sF[tid] = feat[((size_t)b * T_ + t0) * 47 + tid];
    for (int i = tid; i < 47 * 64; i += 256) {
        int f = i >> 6, h = i & 63;
        sW[i] = W1[h * 47 + f];
    }
    __syncthreads();
    int fr = tid >> 6, h = tid & 63;
    float acc = b1[h];
    #pragma unroll
    for (int f = 0; f < 47; ++f)
        acc += sF[fr * 47 + f] * sW[f * 64 + h];
    c1[((size_t)b * T_ + t0 + fr) * 64 + h] = f2bf(fast_tanh(acc));
}

// ---------------------------------------------------------------------------
// Weight prep (bf16 B^T layouts for the prelude GEMMs)
__global__ __launch_bounds__(256) void k_prep(const float* __restrict__ W2,
        const float* __restrict__ Wt, const float* __restrict__ Wih_f,
        short* __restrict__ W2t, short* __restrict__ Wtt, short* __restrict__ Wih) {
    int idx = blockIdx.x * 256 + threadIdx.x;
    if (idx < 256 * 512) {
        int o = idx >> 9, i = idx & 511, d = i >> 8, jj = i & 255;
        W2t[idx] = f2bf(W2[(size_t)o * 512 + jj * 2 + d]);
    }
    {
        int n = idx >> 8, ic = idx & 255, o = n & 255, kp = n >> 8;
        Wtt[idx] = f2bf(Wt[(size_t)ic * 1024 + o * 4 + kp]);
    }
    if (idx < G3_ * CH_)
        Wih[idx] = f2bf(Wih_f[idx]);
}

// ---------------------------------------------------------------------------
// K2: conv2 (k=2 causal) as GEMM M=16384,K=512,N=256 + tanh.
__global__ __launch_bounds__(256) void k2_conv2(const short* __restrict__ c1,
        const short* __restrict__ W2t, const float* __restrict__ b2,
        short* __restrict__ y2) {
    int tid = threadIdx.x, w = tid >> 6, l = tid & 63;
    int lane16 = l & 15, quad = l >> 4;
    int mt = blockIdx.x * 4 + w;
    int row = mt * 16 + lane16;
    int tg = row & 1023;
    const short* Arow = c1 + (size_t)row * 256 - 256;
    bf16x8 zero8 = {0,0,0,0,0,0,0,0};
    bf16x8 af[16];
    #pragma unroll
    for (int kt = 0; kt < 16; ++kt) {
        int i0 = kt * 32 + quad * 8;
        bool masked = (tg == 0) && (kt < 8);
        const short* p = masked ? c1 : (Arow + i0);
        bf16x8 v = *(const bf16x8*)p;
        af[kt] = masked ? zero8 : v;
    }
    #pragma unroll
    for (int nt = 0; nt < 16; ++nt) {
        int n = nt * 16 + lane16;
        f32x4 acc = {0.f, 0.f, 0.f, 0.f};
        const short* Brow = W2t + (size_t)n * 512 + quad * 8;
        #pragma unroll
        for (int kt = 0; kt < 16; ++kt) {
            bf16x8 bf = *(const bf16x8*)(Brow + kt * 32);
            acc = __builtin_amdgcn_mfma_f32_16x16x32_bf16(af[kt], bf, acc, 0, 0, 0);
        }
        float bias = b2[n];
        #pragma unroll
        for (int r = 0; r < 4; ++r) {
            int mrow = mt * 16 + quad * 4 + r;
            y2[(size_t)mrow * 256 + n] = f2bf(fast_tanh(acc[r] + bias));
        }
    }
}

// ---------------------------------------------------------------------------
// K3a: tconv as GEMM M=16384,K=256,N=1024 + tanh -> c3 bf16.
__global__ __launch_bounds__(256) void k3a_tconv(const short* __restrict__ y2,
        const short* __restrict__ Wtt, const float* __restrict__ bt,
        short* __restrict__ c3) {
    int tid = threadIdx.x, w = tid >> 6, l = tid & 63;
    int lane16 = l & 15, quad = l >> 4;
    int mt = blockIdx.x;
    int row = mt * 16 + lane16;
    const short* Arow = y2 + (size_t)row * 256 + quad * 8;
    bf16x8 af[8];
    #pragma unroll
    for (int kt = 0; kt < 8; ++kt) af[kt] = *(const bf16x8*)(Arow + kt * 32);
    #pragma unroll
    for (int nt2 = 0; nt2 < 16; ++nt2) {
        int n = (w * 16 + nt2) * 16 + lane16;
        f32x4 acc = {0.f, 0.f, 0.f, 0.f};
        const short* Brow = Wtt + (size_t)n * 256 + quad * 8;
        #pragma unroll
        for (int kt = 0; kt < 8; ++kt) {
            bf16x8 bf = *(const bf16x8*)(Brow + kt * 32);
            acc = __builtin_amdgcn_mfma_f32_16x16x32_bf16(af[kt], bf, acc, 0, 0, 0);
        }
        int kp = n >> 8, o = n & 255;
        float bias = bt[o];
        #pragma unroll
        for (int r = 0; r < 4; ++r) {
            int mrow = mt * 16 + quad * 4 + r;
            int bb = mrow >> 10, tgg = mrow & 1023;
            c3[(((size_t)bb * TG_ + tgg) * 4 + kp) * 256 + o] =
                f2bf(fast_tanh(acc[r] + bias));
        }
    }
}

// ---------------------------------------------------------------------------
// K3b: x-projection GEMM M=65536,K=256,N=768 (+b_ih) -> gates bf16.
// gates[(b*T+t)*768 + n]
__global__ __launch_bounds__(256) void k3b_xproj(const short* __restrict__ c3,
        const short* __restrict__ Wih, const float* __restrict__ b_ih,
        short* __restrict__ gates) {
    int tid = threadIdx.x, w = tid >> 6, l = tid & 63;
    int lane16 = l & 15, quad = l >> 4;
    int mt = blockIdx.x;
    int row = mt * 16 + lane16;
    const short* Arow = c3 + (size_t)row * 256 + quad * 8;
    bf16x8 af[8];
    #pragma unroll
    for (int kt = 0; kt < 8; ++kt) af[kt] = *(const bf16x8*)(Arow + kt * 32);
    #pragma unroll
    for (int nt2 = 0; nt2 < 12; ++nt2) {
        int n = (w * 12 + nt2) * 16 + lane16;
        f32x4 acc = {0.f, 0.f, 0.f, 0.f};
        const short* Brow = Wih + (size_t)n * 256 + quad * 8;
        #pragma unroll
        for (int kt = 0; kt < 8; ++kt) {
            bf16x8 bf = *(const bf16x8*)(Brow + kt * 32);
            acc = __builtin_amdgcn_mfma_f32_16x16x32_bf16(af[kt], bf, acc, 0, 0, 0);
        }
        float bias = b_ih[n];
        #pragma unroll
        for (int r = 0; r < 4; ++r) {
            int mrow = mt * 16 + quad * 4 + r;
            gates[(size_t)mrow * G3_ + n] = f2bf(acc[r] + bias);
        }
    }
}

// ---------------------------------------------------------------------------
// K4: persistent GRU via MFMA — 1 block per batch, 512 thr, 8 waves.
// The per-step hidden matvec (M=768, K=256, N=1) runs on the matrix pipe:
// mfma_f32_16x16x32_f16 with h broadcast into all 16 B-columns, so every
// D-column equals the matvec (no masking needed). W_hh lives as persistent
// f16 A-fragments: wave w owns M-tiles w*6..w*6+5, frag[6][8] = 192 regs.
// AGPR placement is free here (MFMA reads AGPRs natively — no accvgpr moves,
// unlike the previous v_dot2 version where 128 arch VGPRs forced per-use
// AGPR reads). K fully accumulates inside the MFMA chain, so the old 4-way
// LDS partial reduce disappears. Numerics identical to dot2 path (f16 mul,
// f32 acc). __launch_bounds__(512,2): 2 waves/EU -> 256-reg budget.
__global__ __launch_bounds__(512, 2) void k4_gru_mfma(const float* __restrict__ W_hh,
        const float* __restrict__ b_hh, const short* __restrict__ gates,
        float* __restrict__ out) {
    __shared__ __align__(16) short gxb[2][8][G3_];   // 24KB gate ring (bf16)
    __shared__ __align__(16) float part[G3_];        // 3KB full dot sums
    __shared__ __align__(16) float ob[8 * 256];      // 8KB out staging
    __shared__ __align__(16) _Float16 h_s[256];      // h as f16, linear

    int tid = threadIdx.x, l = tid & 63, w = tid >> 6;
    int lane16 = l & 15, quad = l >> 4;
    int b = blockIdx.x;

    // ---- W_hh -> persistent f16 A-fragments (one-time; fp32 source).
    // A-frag layout for 16x16x32: lane holds A[row=lane16][k=quad*8+e].
    f16x8 frag[6][8];
    #pragma unroll
    for (int mt = 0; mt < 6; ++mt) {
        const float* wrow = W_hh + (size_t)((w * 6 + mt) * 16 + lane16) * 256 + quad * 8;
        #pragma unroll
        for (int kt = 0; kt < 8; ++kt) {
            const float4* p = (const float4*)(wrow + kt * 32);
            float4 x = p[0], y = p[1];
            f16x8 f;
            f[0] = (_Float16)x.x; f[1] = (_Float16)x.y;
            f[2] = (_Float16)x.z; f[3] = (_Float16)x.w;
            f[4] = (_Float16)y.x; f[5] = (_Float16)y.y;
            f[6] = (_Float16)y.z; f[7] = (_Float16)y.w;
            frag[mt][kt] = f;
        }
    }

    float h_reg = 0.f, bhr = 0.f, bhz = 0.f, bhn = 0.f;
    if (tid < 256) {
        bhr = b_hh[tid]; bhz = b_hh[256 + tid]; bhn = b_hh[512 + tid];
        h_s[tid] = (_Float16)0.f;                    // h = 0
    }

    const short* gbase = gates + (size_t)b * T_ * G3_;
    const char* gbytes = (const char*)gbase;

    // prologue: steps 0..7 -> ring half 0
#if HAS_GLL
    {
        char* dst = (char*)&gxb[0][0][0];
        gl_lds16(gbytes + w * 1024 + l * 16, dst + w * 1024);
        if (w < 4) gl_lds16(gbytes + (8 + w) * 1024 + l * 16, dst + (8 + w) * 1024);
    }
#else
    {
        const uint32_t* g32 = (const uint32_t*)gbytes;
        uint32_t* d = (uint32_t*)&gxb[0][0][0];
        #pragma unroll
        for (int i = 0; i < 6; ++i) d[tid + i * 512] = g32[tid + i * 512];
    }
#endif
    __syncthreads();

    float* outb = out + (size_t)b * T_ * CH_;
    for (int s = 0; s < T_; ++s) {
        bool grp0 = ((s & 7) == 0) && (s + 8 < T_);
#if HAS_GLL
        if (grp0) {   // async stage next 8 steps into the other ring half
            const char* src = gbytes + (size_t)(s + 8) * 1536;
            char* dst = (char*)&gxb[((s >> 3) + 1) & 1][0][0];
            gl_lds16(src + w * 1024 + l * 16, dst + w * 1024);
            if (w < 4) gl_lds16(src + (8 + w) * 1024 + l * 16, dst + (8 + w) * 1024);
        }
#else
        uint32_t pf[6];
        if (grp0) {
            const uint32_t* src = (const uint32_t*)(gbytes + (size_t)(s + 8) * 1536);
            #pragma unroll
            for (int i = 0; i < 6; ++i) pf[i] = src[tid + i * 512];
        }
#endif

        // ---- MFMA matvec: B-frag = h broadcast (lane holds h[kt*32+quad*8+e],
        // same for all 16 columns -> 16 lanes/group read same LDS addr: free
        // broadcast). acc chains over K inside the MFMA pipe.
        f32x4 acc[6];
        #pragma unroll
        for (int mt = 0; mt < 6; ++mt) acc[mt] = (f32x4){0.f, 0.f, 0.f, 0.f};
        #pragma unroll
        for (int kt = 0; kt < 8; ++kt) {
            f16x8 hb = *(const f16x8*)&h_s[kt * 32 + quad * 8];
            #pragma unroll
            for (int mt = 0; mt < 6; ++mt)
                acc[mt] = __builtin_amdgcn_mfma_f32_16x16x32_f16(frag[mt][kt], hb, acc[mt], 0, 0, 0);
        }
        // D: row = quad*4 + r (col replicated). Lanes 0/16/32/48 write f32x4.
        if (lane16 == 0) {
            #pragma unroll
            for (int mt = 0; mt < 6; ++mt)
                *(f32x4*)&part[(w * 6 + mt) * 16 + quad * 4] = acc[mt];
        }
        __syncthreads();   // b1

#if !HAS_GLL
        if (grp0) {
            uint32_t* d = (uint32_t*)&gxb[((s >> 3) + 1) & 1][0][0];
            #pragma unroll
            for (int i = 0; i < 6; ++i) d[tid + i * 512] = pf[i];
        }
#endif
        // ---- elementwise on threads < 256 (one wave per SIMD)
        if (tid < 256) {
            const short* gx = &gxb[(s >> 3) & 1][s & 7][0];
            float gr = part[tid];
            float gz = part[256 + tid];
            float gn = part[512 + tid];
            float xr = bf2f(gx[tid]), xz = bf2f(gx[256 + tid]), xn = bf2f(gx[512 + tid]);
            float r = fast_sigmoid(xr + gr + bhr);
            float z = fast_sigmoid(xz + gz + bhz);
            float nn = fast_tanh(xn + r * (gn + bhn));
            h_reg = (1.f - z) * nn + z * h_reg;
            h_s[tid] = (_Float16)h_reg;
            ob[(s & 7) * 256 + tid] = h_reg;
        }
        __syncthreads();   // b2

        // ---- out flush once per 8 steps, coalesced f32x4
        if ((s & 7) == 7) {
            f32x4 v = *(const f32x4*)&ob[tid * 4];
            *(f32x4*)&outb[(size_t)(s - 7 + (tid >> 6)) * 256 + (tid & 63) * 4] = v;
        }
    }
}

// ---------------------------------------------------------------------------
extern "C" void kernel_launch(void* const* d_in, const int* in_sizes, int n_in,
                              void* d_out, int out_size, void* d_ws, size_t ws_size,
                              hipStream_t stream) {
    const float* feat  = (const float*)d_in[0];
    const float* W1    = (const float*)d_in[1];
    const float* b1    = (const float*)d_in[2];
    const float* W2    = (const float*)d_in[3];
    const float* b2    = (const float*)d_in[4];
    const float* Wt    = (const float*)d_in[5];
    const float* bt    = (const float*)d_in[6];
    const float* Wih_f = (const float*)d_in[7];
    const float* Whh   = (const float*)d_in[8];
    const float* bih   = (const float*)d_in[9];
    const float* bhh   = (const float*)d_in[10];
    float* out = (float*)d_out;

    // ws layout (135.4 MB):
    //   [0, 33.5M)      c3 bf16 (c1 aliases first 8.4M; c1 dead after K2)
    //   [33.5M, 134.2M) gates bf16 (y2 aliases first 8.4M; y2 dead after K3a)
    //   [134.2M, ...)   W2t / Wtt / Wih bf16
    char* ws = (char*)d_ws;
    short* c3    = (short*)(ws);
    short* c1    = (short*)(ws);
    short* gates = (short*)(ws + 33554432);
    short* y2    = (short*)(ws + 33554432);
    short* W2t   = (short*)(ws + 134217728);
    short* Wtt   = (short*)(ws + 134217728 + 262144);
    short* Wih   = (short*)(ws + 134217728 + 262144 + 524288);

    k1_conv1   <<<16384, 256, 0, stream>>>(feat, W1, b1, c1);
    k_prep     <<<1024, 256, 0, stream>>>(W2, Wt, Wih_f, W2t, Wtt, Wih);
    k2_conv2   <<<256,  256, 0, stream>>>(c1, W2t, b2, y2);
    k3a_tconv  <<<1024, 256, 0, stream>>>(y2, Wtt, bt, c3);      // kills c1
    k3b_xproj  <<<4096, 256, 0, stream>>>(c3, Wih, bih, gates);  // kills y2
    k4_gru_mfma<<<16,   512, 0, stream>>>(Whh, bhh, gates, out);
}

// Round 2
// 5392.699 us; speedup vs baseline: 1.0687x; 1.0687x over previous
//
#include <hip/hip_runtime.h>
#include <hip/hip_bf16.h>
#include <stdint.h>

// Problem dims
#define B_   16
#define T_   4096
#define F_   47
#define HID_ 64
#define CH_  256
#define TG_  1024   // T/4
#define G3_  768    // 3*CH

using bf16x8 = __attribute__((ext_vector_type(8))) short;  // 8 bf16 (4 VGPRs)
using f32x4  = __attribute__((ext_vector_type(4))) float;  // 4 fp32 acc
using f16x8  = __attribute__((ext_vector_type(8))) _Float16;
using h2     = __attribute__((ext_vector_type(2))) _Float16;

__device__ __forceinline__ short f2bf(float f) {
    union { float f; uint32_t u; } v; v.f = f;
    uint32_t u = v.u;
    uint32_t r = (u + 0x7fffu + ((u >> 16) & 1u)) >> 16;   // RNE
    return (short)r;
}
__device__ __forceinline__ float bf2f(short s) {
    union { uint32_t u; float f; } v; v.u = ((uint32_t)(uint16_t)s) << 16;
    return v.f;
}
__device__ __forceinline__ float fast_tanh(float x) {
    float e = __expf(2.f * x);           // inf-safe
    return 1.f - 2.f / (e + 1.f);
}
__device__ __forceinline__ float fast_sigmoid(float x) {
    return 1.f / (1.f + __expf(-x));
}

#if __has_builtin(__builtin_amdgcn_fdot2)
#define FDOT2(a, b, c) __builtin_amdgcn_fdot2((a), (b), (c), false)
#else
__device__ __forceinline__ float fdot2_emul(h2 a, h2 b, float c) {
    return c + (float)a[0] * (float)b[0] + (float)a[1] * (float)b[1];
}
#define FDOT2(a, b, c) fdot2_emul((a), (b), (c))
#endif

// DPP quad-perm add: butterfly reduce across the 4 lanes of a quad (no LDS).
template <int CTRL>
__device__ __forceinline__ float dpp_add(float x) {
    union { float f; int i; } a, b;
    a.f = x;
    b.i = __builtin_amdgcn_update_dpp(0, a.i, CTRL, 0xf, 0xf, true);
    return x + b.f;
}

#if __has_builtin(__builtin_amdgcn_global_load_lds)
#define HAS_GLL 1
__device__ __forceinline__ void gl_lds16(const void* g, void* l) {
    __builtin_amdgcn_global_load_lds(
        (const __attribute__((address_space(1))) uint32_t*)g,
        (__attribute__((address_space(3))) uint32_t*)l, 16, 0, 0);
}
#else
#define HAS_GLL 0
#endif

// ---------------------------------------------------------------------------
// K1: conv1 (pointwise 47->64) + tanh, fp32 VALU, writes c1 as bf16
__global__ __launch_bounds__(256) void k1_conv1(const float* __restrict__ feat,
        const float* __restrict__ W1, const float* __restrict__ b1,
        short* __restrict__ c1) {
    __shared__ float sW[47 * 64];
    __shared__ float sF[4 * 47];
    int tid = threadIdx.x;
    int b = blockIdx.x >> 10, t0 = (blockIdx.x & 1023) * 4;
    if (tid < 188) sF[tid] = feat[((size_t)b * T_ + t0) * 47 + tid];
    for (int i = tid; i < 47 * 64; i += 256) {
        int f = i >> 6, h = i & 63;
        sW[i] = W1[h * 47 + f];
    }
    __syncthreads();
    int fr = tid >> 6, h = tid & 63;
    float acc = b1[h];
    #pragma unroll
    for (int f = 0; f < 47; ++f)
        acc += sF[fr * 47 + f] * sW[f * 64 + h];
    c1[((size_t)b * T_ + t0 + fr) * 64 + h] = f2bf(fast_tanh(acc));
}

// ---------------------------------------------------------------------------
// Weight prep (bf16 B^T layouts for the prelude GEMMs)
__global__ __launch_bounds__(256) void k_prep(const float* __restrict__ W2,
        const float* __restrict__ Wt, const float* __restrict__ Wih_f,
        short* __restrict__ W2t, short* __restrict__ Wtt, short* __restrict__ Wih) {
    int idx = blockIdx.x * 256 + threadIdx.x;
    if (idx < 256 * 512) {
        int o = idx >> 9, i = idx & 511, d = i >> 8, jj = i & 255;
        W2t[idx] = f2bf(W2[(size_t)o * 512 + jj * 2 + d]);
    }
    {
        int n = idx >> 8, ic = idx & 255, o = n & 255, kp = n >> 8;
        Wtt[idx] = f2bf(Wt[(size_t)ic * 1024 + o * 4 + kp]);
    }
    if (idx < G3_ * CH_)
        Wih[idx] = f2bf(Wih_f[idx]);
}

// ---------------------------------------------------------------------------
// K2: conv2 (k=2 causal) as GEMM M=16384,K=512,N=256 + tanh.
__global__ __launch_bounds__(256) void k2_conv2(const short* __restrict__ c1,
        const short* __restrict__ W2t, const float* __restrict__ b2,
        short* __restrict__ y2) {
    int tid = threadIdx.x, w = tid >> 6, l = tid & 63;
    int lane16 = l & 15, quad = l >> 4;
    int mt = blockIdx.x * 4 + w;
    int row = mt * 16 + lane16;
    int tg = row & 1023;
    const short* Arow = c1 + (size_t)row * 256 - 256;
    bf16x8 zero8 = {0,0,0,0,0,0,0,0};
    bf16x8 af[16];
    #pragma unroll
    for (int kt = 0; kt < 16; ++kt) {
        int i0 = kt * 32 + quad * 8;
        bool masked = (tg == 0) && (kt < 8);
        const short* p = masked ? c1 : (Arow + i0);
        bf16x8 v = *(const bf16x8*)p;
        af[kt] = masked ? zero8 : v;
    }
    #pragma unroll
    for (int nt = 0; nt < 16; ++nt) {
        int n = nt * 16 + lane16;
        f32x4 acc = {0.f, 0.f, 0.f, 0.f};
        const short* Brow = W2t + (size_t)n * 512 + quad * 8;
        #pragma unroll
        for (int kt = 0; kt < 16; ++kt) {
            bf16x8 bf = *(const bf16x8*)(Brow + kt * 32);
            acc = __builtin_amdgcn_mfma_f32_16x16x32_bf16(af[kt], bf, acc, 0, 0, 0);
        }
        float bias = b2[n];
        #pragma unroll
        for (int r = 0; r < 4; ++r) {
            int mrow = mt * 16 + quad * 4 + r;
            y2[(size_t)mrow * 256 + n] = f2bf(fast_tanh(acc[r] + bias));
        }
    }
}

// ---------------------------------------------------------------------------
// K3a: tconv as GEMM M=16384,K=256,N=1024 + tanh -> c3 bf16.
__global__ __launch_bounds__(256) void k3a_tconv(const short* __restrict__ y2,
        const short* __restrict__ Wtt, const float* __restrict__ bt,
        short* __restrict__ c3) {
    int tid = threadIdx.x, w = tid >> 6, l = tid & 63;
    int lane16 = l & 15, quad = l >> 4;
    int mt = blockIdx.x;
    int row = mt * 16 + lane16;
    const short* Arow = y2 + (size_t)row * 256 + quad * 8;
    bf16x8 af[8];
    #pragma unroll
    for (int kt = 0; kt < 8; ++kt) af[kt] = *(const bf16x8*)(Arow + kt * 32);
    #pragma unroll
    for (int nt2 = 0; nt2 < 16; ++nt2) {
        int n = (w * 16 + nt2) * 16 + lane16;
        f32x4 acc = {0.f, 0.f, 0.f, 0.f};
        const short* Brow = Wtt + (size_t)n * 256 + quad * 8;
        #pragma unroll
        for (int kt = 0; kt < 8; ++kt) {
            bf16x8 bf = *(const bf16x8*)(Brow + kt * 32);
            acc = __builtin_amdgcn_mfma_f32_16x16x32_bf16(af[kt], bf, acc, 0, 0, 0);
        }
        int kp = n >> 8, o = n & 255;
        float bias = bt[o];
        #pragma unroll
        for (int r = 0; r < 4; ++r) {
            int mrow = mt * 16 + quad * 4 + r;
            int bb = mrow >> 10, tgg = mrow & 1023;
            c3[(((size_t)bb * TG_ + tgg) * 4 + kp) * 256 + o] =
                f2bf(fast_tanh(acc[r] + bias));
        }
    }
}

// ---------------------------------------------------------------------------
// K3b: x-projection GEMM M=65536,K=256,N=768 (+b_ih) -> gates bf16.
// gates[(b*T+t)*768 + n]
__global__ __launch_bounds__(256) void k3b_xproj(const short* __restrict__ c3,
        const short* __restrict__ Wih, const float* __restrict__ b_ih,
        short* __restrict__ gates) {
    int tid = threadIdx.x, w = tid >> 6, l = tid & 63;
    int lane16 = l & 15, quad = l >> 4;
    int mt = blockIdx.x;
    int row = mt * 16 + lane16;
    const short* Arow = c3 + (size_t)row * 256 + quad * 8;
    bf16x8 af[8];
    #pragma unroll
    for (int kt = 0; kt < 8; ++kt) af[kt] = *(const bf16x8*)(Arow + kt * 32);
    #pragma unroll
    for (int nt2 = 0; nt2 < 12; ++nt2) {
        int n = (w * 12 + nt2) * 16 + lane16;
        f32x4 acc = {0.f, 0.f, 0.f, 0.f};
        const short* Brow = Wih + (size_t)n * 256 + quad * 8;
        #pragma unroll
        for (int kt = 0; kt < 8; ++kt) {
            bf16x8 bf = *(const bf16x8*)(Brow + kt * 32);
            acc = __builtin_amdgcn_mfma_f32_16x16x32_bf16(af[kt], bf, acc, 0, 0, 0);
        }
        float bias = b_ih[n];
        #pragma unroll
        for (int r = 0; r < 4; ++r) {
            int mrow = mt * 16 + quad * 4 + r;
            gates[(size_t)mrow * G3_ + n] = f2bf(acc[r] + bias);
        }
    }
}

// ---------------------------------------------------------------------------
// K4: persistent GRU via VALU v_dot2_f32_f16 — 1 block/batch, 512 thr, 8 waves.
// Quad-aligned ownership: thread (q=tid&3, n0=tid>>2) computes the K-quarter
// [64q,64q+64) partial of rows n0+k*128 (k<6) == channels {n0, n0+128} x
// {r,z,n}. Cross-q reduce = 2 DPP quad_perm adds (no LDS, no barrier), after
// which the quad holds r,z,n for its 2 channels locally -> elementwise runs
// in ALL 8 waves (lanes q<2), b_hh folded into acc init. ONE barrier/step;
// h_s and ob are double-buffered to keep the single-barrier region race-free.
// Weights: wreg[6][32] h2 = 192 regs; working set kept ~36 so the allocator
// can place everything in the 256 arch VGPRs (launch_bounds(512,2)) and
// avoid the round-0 AGPR-read tax.
__global__ __launch_bounds__(512, 2) void k4_gru_dot2(const float* __restrict__ W_hh,
        const float* __restrict__ b_hh, const short* __restrict__ gates,
        float* __restrict__ out) {
    __shared__ __align__(16) short gxb[2][8][G3_];   // 24KB gate ring (bf16)
    __shared__ __align__(16) float ob[2][8 * 256];   // 16KB out staging (dbuf)
    __shared__ __align__(16) short hq_s[2][4 * 72];  // h as f16, padded quarters, dbuf

    int tid = threadIdx.x, l = tid & 63, w = tid >> 6;
    int q = tid & 3, n0 = tid >> 2;                  // n0 in 0..127
    int b = blockIdx.x;

    // ---- W_hh -> f16-pair registers (one-time; fp32 source)
    h2 wreg[6][32];
    #pragma unroll
    for (int k = 0; k < 6; ++k) {
        const float2* row = (const float2*)(W_hh + ((size_t)(n0 + k * 128)) * 256 + q * 64);
        #pragma unroll
        for (int j = 0; j < 32; ++j) {
            float2 v = row[j];
            h2 p; p[0] = (_Float16)v.x; p[1] = (_Float16)v.y;
            wreg[k][j] = p;
        }
    }

    // ---- bias fold: q==0 lane seeds each row's accumulator with b_hh[row]
    float bh[6];
    #pragma unroll
    for (int k = 0; k < 6; ++k)
        bh[k] = (q == 0) ? b_hh[n0 + k * 128] : 0.f;

    float h_reg = 0.f;
    int c = n0 + (q & 1) * 128;                      // ew channel for lanes q<2

    if (tid < 288) hq_s[0][tid] = 0;                 // h = 0 (f16), buf 0 only

    const short* gbase = gates + (size_t)b * T_ * G3_;
    const char* gbytes = (const char*)gbase;

    // prologue: steps 0..7 -> ring half 0
#if HAS_GLL
    {
        char* dst = (char*)&gxb[0][0][0];
        gl_lds16(gbytes + w * 1024 + l * 16, dst + w * 1024);
        if (w < 4) gl_lds16(gbytes + (8 + w) * 1024 + l * 16, dst + (8 + w) * 1024);
    }
#else
    {
        const uint32_t* g32 = (const uint32_t*)gbytes;
        uint32_t* d = (uint32_t*)&gxb[0][0][0];
        #pragma unroll
        for (int i = 0; i < 6; ++i) d[tid + i * 512] = g32[tid + i * 512];
    }
#endif
    __syncthreads();

    float* outb = out + (size_t)b * T_ * CH_;
    for (int s = 0; s < T_; ++s) {
        bool grp0 = ((s & 7) == 0) && (s + 8 < T_);
#if HAS_GLL
        if (grp0) {   // async stage next 8 steps into the other ring half
            const char* src = gbytes + (size_t)(s + 8) * 1536;
            char* dst = (char*)&gxb[((s >> 3) + 1) & 1][0][0];
            gl_lds16(src + w * 1024 + l * 16, dst + w * 1024);
            if (w < 4) gl_lds16(src + (8 + w) * 1024 + l * 16, dst + (8 + w) * 1024);
        }
#else
        uint32_t pf[6];
        if (grp0) {
            const uint32_t* src = (const uint32_t*)(gbytes + (size_t)(s + 8) * 1536);
            #pragma unroll
            for (int i = 0; i < 6; ++i) pf[i] = src[tid + i * 512];
        }
#endif

        // ---- dot2 phase: stream h-quarter 16B at a time (4 live regs), 192 fdot2
        float acc[6];
        #pragma unroll
        for (int k = 0; k < 6; ++k) acc[k] = bh[k];
        const short* hb = &hq_s[s & 1][q * 72];
        #pragma unroll
        for (int g2 = 0; g2 < 8; ++g2) {
            f16x8 v = *(const f16x8*)(hb + g2 * 8);
            #pragma unroll
            for (int p2 = 0; p2 < 4; ++p2) {
                h2 hv; hv[0] = v[p2 * 2]; hv[1] = v[p2 * 2 + 1];
                #pragma unroll
                for (int k = 0; k < 6; ++k)
                    acc[k] = FDOT2(wreg[k][g2 * 4 + p2], hv, acc[k]);
            }
        }

        // ---- quad butterfly: full K-sum in every lane of the quad (no LDS)
        #pragma unroll
        for (int k = 0; k < 6; ++k) {
            acc[k] = dpp_add<0xB1>(acc[k]);   // quad_perm [1,0,3,2]
            acc[k] = dpp_add<0x4E>(acc[k]);   // quad_perm [2,3,0,1]
        }

#if !HAS_GLL
        if (grp0) {
            uint32_t* d = (uint32_t*)&gxb[((s >> 3) + 1) & 1][0][0];
            #pragma unroll
            for (int i = 0; i < 6; ++i) d[tid + i * 512] = pf[i];
        }
#endif
        // ---- elementwise: lanes q<2, all 8 waves in parallel
        if (q < 2) {
            const short* gx = &gxb[(s >> 3) & 1][s & 7][0];
            float gr = (q & 1) ? acc[1] : acc[0];
            float gz = (q & 1) ? acc[3] : acc[2];
            float gn = (q & 1) ? acc[5] : acc[4];
            float xr = bf2f(gx[c]), xz = bf2f(gx[256 + c]), xn = bf2f(gx[512 + c]);
            float r = fast_sigmoid(xr + gr);
            float z = fast_sigmoid(xz + gz);
            float nn = fast_tanh(xn + r * gn);
            h_reg = (1.f - z) * nn + z * h_reg;
            union { _Float16 f; short u; } cv; cv.f = (_Float16)h_reg;
            hq_s[(s + 1) & 1][(c >> 6) * 72 + (c & 63)] = cv.u;
            ob[(s >> 3) & 1][(s & 7) * 256 + c] = h_reg;
        }
        __syncthreads();   // single barrier per step

        // ---- out flush once per 8 steps, coalesced f32x4
        if ((s & 7) == 7) {
            f32x4 v = *(const f32x4*)&ob[(s >> 3) & 1][tid * 4];
            *(f32x4*)&outb[(size_t)(s - 7 + (tid >> 6)) * 256 + (tid & 63) * 4] = v;
        }
    }
}

// ---------------------------------------------------------------------------
extern "C" void kernel_launch(void* const* d_in, const int* in_sizes, int n_in,
                              void* d_out, int out_size, void* d_ws, size_t ws_size,
                              hipStream_t stream) {
    const float* feat  = (const float*)d_in[0];
    const float* W1    = (const float*)d_in[1];
    const float* b1    = (const float*)d_in[2];
    const float* W2    = (const float*)d_in[3];
    const float* b2    = (const float*)d_in[4];
    const float* Wt    = (const float*)d_in[5];
    const float* bt    = (const float*)d_in[6];
    const float* Wih_f = (const float*)d_in[7];
    const float* Whh   = (const float*)d_in[8];
    const float* bih   = (const float*)d_in[9];
    const float* bhh   = (const float*)d_in[10];
    float* out = (float*)d_out;

    // ws layout (135.4 MB):
    //   [0, 33.5M)      c3 bf16 (c1 aliases first 8.4M; c1 dead after K2)
    //   [33.5M, 134.2M) gates bf16 (y2 aliases first 8.4M; y2 dead after K3a)
    //   [134.2M, ...)   W2t / Wtt / Wih bf16
    char* ws = (char*)d_ws;
    short* c3    = (short*)(ws);
    short* c1    = (short*)(ws);
    short* gates = (short*)(ws + 33554432);
    short* y2    = (short*)(ws + 33554432);
    short* W2t   = (short*)(ws + 134217728);
    short* Wtt   = (short*)(ws + 134217728 + 262144);
    short* Wih   = (short*)(ws + 134217728 + 262144 + 524288);

    k1_conv1   <<<16384, 256, 0, stream>>>(feat, W1, b1, c1);
    k_prep     <<<1024, 256, 0, stream>>>(W2, Wt, Wih_f, W2t, Wtt, Wih);
    k2_conv2   <<<256,  256, 0, stream>>>(c1, W2t, b2, y2);
    k3a_tconv  <<<1024, 256, 0, stream>>>(y2, Wtt, bt, c3);      // kills c1
    k3b_xproj  <<<4096, 256, 0, stream>>>(c3, Wih, bih, gates);  // kills y2
    k4_gru_dot2<<<16,   512, 0, stream>>>(Whh, bhh, gates, out);
}